// Round 4
// baseline (121.351 us; speedup 1.0000x reference)
//
#include <hip/hip_runtime.h>

// Implicit-GEMM conv2d via bf16 MFMA, ws pre-pack + 8-phase pipelined main loop
// (m201-family schedule): tile 256x256xBK64, 512 thr, 8 waves (2Mx4N),
// per-wave 128x64, acc[8][4]. LDS 2 x 64KB. Counted vmcnt(4) at K-tile
// boundary only; 4 quadrant phases/K-tile with per-phase barrier+setprio.
//   A' [256][1152] bf16, k = tap*128+ci   (from w [256][128][3][3] f32)
//   xp [32][64][64][128] bf16 (NHWC)       (from x [32][128][64][64] f32)

using bf16x8 = __attribute__((ext_vector_type(8))) __bf16;
using f32x4  = __attribute__((ext_vector_type(4))) float;

constexpr int CIN  = 128;
constexpr int HW   = 64;
constexpr int COUT = 256;
constexpr int OW   = 62;
constexpr int NS   = 62 * 62;          // 3844
constexpr int NTOT = 32 * NS;          // 123008
constexpr int KTOT = 9 * CIN;          // 1152
constexpr int BM = 256, BN = 256, BK = 64;
constexpr int NT = KTOT / BK;          // 18 K-tiles
constexpr int NBLK = (NTOT + BN - 1) / BN;   // 481

constexpr size_t AP_BYTES = (size_t)COUT * KTOT * 2;            // 589824
constexpr size_t XP_BYTES = (size_t)32 * HW * HW * CIN * 2;     // 33554432
constexpr size_t WS_NEEDED = AP_BYTES + XP_BYTES;

constexpr int BUF  = 65536;            // per K-tile buffer: A 32KB + B 32KB
constexpr int BOFF = 32768;            // B offset inside buffer

__device__ __forceinline__ unsigned short f2bf(float f) {
  unsigned u = __float_as_uint(f);
  u += 0x7fffu + ((u >> 16) & 1u);     // RNE
  return (unsigned short)(u >> 16);
}
__device__ __forceinline__ unsigned pack2(float a, float b) {
  return (unsigned)f2bf(a) | ((unsigned)f2bf(b) << 16);
}

__device__ __forceinline__ void gld16(const void* g, void* l) {
  __builtin_amdgcn_global_load_lds(
      (const __attribute__((address_space(1))) unsigned int*)g,
      (__attribute__((address_space(3))) unsigned int*)l, 16, 0, 0);
}

// ---------------- prepack kernels ----------------

__global__ __launch_bounds__(256)
void prepack_w(const float* __restrict__ w, unsigned* __restrict__ ap32) {
  const int idx = blockIdx.x * 256 + threadIdx.x;     // 0..147455
  const int co  = idx / 576;
  const int k2  = idx - co * 576;
  const int k   = k2 * 2;
  const int tap = k >> 7;
  const int ci  = k & 127;
  const float v0 = w[(co * 128 + ci) * 9 + tap];
  const float v1 = w[(co * 128 + ci + 1) * 9 + tap];
  ap32[idx] = pack2(v0, v1);
}

__global__ __launch_bounds__(256)
void prepack_x(const float* __restrict__ x, unsigned* __restrict__ xp32) {
  const int bh = blockIdx.x;           // b*64 + h
  const int b  = bh >> 6, h = bh & 63;
  const int t  = threadIdx.x;
  const int c  = t & 63;               // ci-pair index (ci = 2c, 2c+1)
  const int w0 = (t >> 6) * 16;

  const float* p0 = x + (((size_t)(b * 128 + 2 * c) * HW) + h) * HW + w0;
  const float* p1 = p0 + (size_t)HW * HW;
  float r0[16], r1[16];
#pragma unroll
  for (int j = 0; j < 4; ++j) {
    *reinterpret_cast<float4*>(&r0[j * 4]) = reinterpret_cast<const float4*>(p0)[j];
    *reinterpret_cast<float4*>(&r1[j * 4]) = reinterpret_cast<const float4*>(p1)[j];
  }
  unsigned* o = xp32 + ((size_t)bh * HW + w0) * 64 + c;
#pragma unroll
  for (int j = 0; j < 16; ++j)
    o[j * 64] = pack2(r0[j], r1[j]);
}

// ---------------- main kernel ----------------

__global__ __launch_bounds__(512, 2)
void conv_main(const unsigned short* __restrict__ Ap,
               const unsigned short* __restrict__ Xp,
               float* __restrict__ out) {
  // Buffer layout: rows of 64 bf16 (128B = 8 x 16B slots); LDS slot s of row r
  // holds global k-slot g = s ^ (r&7); staged linearly (source pre-swizzled).
  __shared__ __align__(16) char lds[2 * BUF];   // 128 KiB

  const int tid  = threadIdx.x;
  const int lane = tid & 63;
  const int wid  = tid >> 6;       // 0..7
  const int wm   = wid & 1;        // A half: rows wm*128..+127
  const int wn   = wid >> 1;       // B slice: rows wn*64..+63
  const int n_base = blockIdx.x * BN;

  // ---- staging source offsets (element units); call j covers rows j*64..+63
  const int l3  = lane >> 3;
  const int sw8 = ((lane & 7) ^ l3) * 8;     // pre-swizzled slot
  int aoff[4];
  unsigned xoff[4];
#pragma unroll
  for (int j = 0; j < 4; ++j) {
    const int r = j * 64 + wid * 8 + l3;
    aoff[j] = r * KTOT + sw8;
    unsigned n = n_base + r;
    if (n >= NTOT) n = NTOT - 1;             // tail block: clamp (stores guarded)
    const unsigned bi = n / NS;
    const unsigned s0 = n - bi * NS;
    const unsigned oh = s0 / OW;
    const unsigned ww = s0 - oh * OW;
    xoff[j] = ((bi * HW + oh) * HW + ww) * CIN + sw8;
  }

  // ---- fragment read addressing (byte offsets within buffer) ----
  const int fr = lane & 15;
  const int gl = lane >> 4;
  const int s0b = ((gl)     ^ (fr & 7)) * 16;   // kk=0 slot
  const int s1b = ((4 + gl) ^ (fr & 7)) * 16;   // kk=1 slot
  const int abase = (wm * 128 + fr) * 128;
  const int bbase = BOFF + (wn * 64 + fr) * 128;

  f32x4 acc[8][4] = {};
  bf16x8 aq[8];          // [mi' * 2 + kk], current m-quadrant
  bf16x8 b0q[4], b1q[4]; // [ni' * 2 + kk], n-quadrant 0 / 1

  auto STAGE_A = [&](int tt, char* dst) {
#pragma unroll
    for (int j = 0; j < 4; ++j)
      gld16(Ap + aoff[j] + tt * 64, dst + (j * 64 + wid * 8) * 128);
  };
  auto STAGE_B = [&](int tt, char* dst) {
    const int tap = tt >> 1;
    const int kh  = tap / 3;
    const int kw  = tap - kh * 3;
    const int xk  = (kh * HW + kw) * CIN + (tt & 1) * 64;
#pragma unroll
    for (int j = 0; j < 4; ++j)
      gld16(Xp + xoff[j] + xk, dst + BOFF + (j * 64 + wid * 8) * 128);
  };

  auto LOAD_A = [&](const char* cur, int mq) {
#pragma unroll
    for (int mi = 0; mi < 4; ++mi) {
      aq[mi * 2 + 0] = *reinterpret_cast<const bf16x8*>(cur + abase + mq * 8192 + mi * 2048 + s0b);
      aq[mi * 2 + 1] = *reinterpret_cast<const bf16x8*>(cur + abase + mq * 8192 + mi * 2048 + s1b);
    }
  };
  auto LOAD_B = [&](const char* cur, int nq, bf16x8* bq) {
#pragma unroll
    for (int ni = 0; ni < 2; ++ni) {
      bq[ni * 2 + 0] = *reinterpret_cast<const bf16x8*>(cur + bbase + nq * 4096 + ni * 2048 + s0b);
      bq[ni * 2 + 1] = *reinterpret_cast<const bf16x8*>(cur + bbase + nq * 4096 + ni * 2048 + s1b);
    }
  };
  auto MFMA16 = [&](int mq, int nq, const bf16x8* bq) {
    __builtin_amdgcn_s_setprio(1);
#pragma unroll
    for (int mi = 0; mi < 4; ++mi)
#pragma unroll
      for (int ni = 0; ni < 2; ++ni)
#pragma unroll
        for (int kk = 0; kk < 2; ++kk)
          acc[mq * 4 + mi][nq * 2 + ni] = __builtin_amdgcn_mfma_f32_16x16x32_bf16(
              aq[mi * 2 + kk], bq[ni * 2 + kk], acc[mq * 4 + mi][nq * 2 + ni], 0, 0, 0);
    __builtin_amdgcn_s_setprio(0);
  };

  // ---- prologue: stage K-tile 0 into buf0 (8 loads/thread in flight) ----
  STAGE_A(0, lds);
  STAGE_B(0, lds);

#pragma unroll
  for (int t = 0; t < NT; ++t) {
    char* cur = lds + (t & 1) * BUF;
    char* nxt = lds + ((t + 1) & 1) * BUF;

    // ---- Phase A: quadrant (m0, n0); stage A(t+1) ----
    if (t < NT - 1) {
      STAGE_A(t + 1, nxt);
      asm volatile("s_waitcnt vmcnt(4)" ::: "memory");   // K-tile t fully landed
    } else {
      asm volatile("s_waitcnt vmcnt(0)" ::: "memory");
    }
    __builtin_amdgcn_s_barrier();
    __builtin_amdgcn_sched_barrier(0);
    LOAD_A(cur, 0);
    LOAD_B(cur, 0, b0q);
    asm volatile("s_waitcnt lgkmcnt(0)" ::: "memory");
    __builtin_amdgcn_sched_barrier(0);
    MFMA16(0, 0, b0q);
    __builtin_amdgcn_s_barrier();

    // ---- Phase B: quadrant (m0, n1); stage B(t+1) ----
    LOAD_B(cur, 1, b1q);
    if (t < NT - 1) STAGE_B(t + 1, nxt);
    __builtin_amdgcn_s_barrier();
    asm volatile("s_waitcnt lgkmcnt(0)" ::: "memory");
    __builtin_amdgcn_sched_barrier(0);
    MFMA16(0, 1, b1q);
    __builtin_amdgcn_s_barrier();

    // ---- Phase C: quadrant (m1, n1) ----
    LOAD_A(cur, 1);
    __builtin_amdgcn_s_barrier();
    asm volatile("s_waitcnt lgkmcnt(0)" ::: "memory");
    __builtin_amdgcn_sched_barrier(0);
    MFMA16(1, 1, b1q);
    __builtin_amdgcn_s_barrier();

    // ---- Phase D: quadrant (m1, n0) — all operands in registers ----
    MFMA16(1, 0, b0q);
    __builtin_amdgcn_s_barrier();
  }

  // ---- epilogue: D col = lane&15 (n), row = (lane>>4)*4 + r (co) ----
#pragma unroll
  for (int ni = 0; ni < 4; ++ni) {
    const unsigned n = n_base + wn * 64 + ni * 16 + fr;
    if (n >= NTOT) continue;
    const unsigned b2 = n / NS;
    const unsigned s2 = n - b2 * NS;
    float* op = out + (size_t)b2 * (COUT * NS) + s2
                    + (size_t)(wm * 128 + gl * 4) * NS;
#pragma unroll
    for (int mi = 0; mi < 8; ++mi)
#pragma unroll
      for (int r = 0; r < 4; ++r)
        op[(mi * 16 + r) * NS] = acc[mi][ni][r];
  }
}

// ---------------- fallback (no-ws path, round-1 proven) ----------------

__global__ __launch_bounds__(256)
void conv_fallback(const float* __restrict__ x, const float* __restrict__ w,
                   float* __restrict__ out) {
  __shared__ __align__(16) unsigned short As[128 * 32];
  __shared__ __align__(16) unsigned short Bs[128 * 32];

  const int t    = threadIdx.x;
  const int lane = t & 63;
  const int wid  = t >> 6;
  const int wm   = wid >> 1;
  const int wn   = wid & 1;
  const int co_base = blockIdx.x * 128;
  const int n_base  = blockIdx.y * 128;

  const int bn  = t & 127;
  const int bg0 = t >> 7;
  const unsigned n0   = n_base + bn;
  const unsigned bidx = n0 / NS;
  const unsigned s0   = n0 - bidx * NS;
  const unsigned oh   = s0 / OW;
  const unsigned ow   = s0 - oh * OW;
  const float* xb = x + (bidx * (CIN * HW * HW) + oh * HW + ow);

  const int am  = t & 127;
  const int ag0 = (t >> 7) * 2;
  const float* wb = w + (co_base + am) * KTOT;

  f32x4 acc[4][4] = {};

  for (int ks = 0; ks < 36; ++ks) {
    const int tap = ks >> 2;
    const int ci0 = (ks & 3) * 32;
    const int kh  = tap / 3;
    const int kw  = tap - kh * 3;
    const int xo  = kh * HW + kw;

    float av[2][8], bv[2][8];
#pragma unroll
    for (int gi = 0; gi < 2; ++gi) {
      const int g = ag0 + gi;
#pragma unroll
      for (int j = 0; j < 8; ++j)
        av[gi][j] = wb[(ci0 + g * 8 + j) * 9 + tap];
    }
#pragma unroll
    for (int gi = 0; gi < 2; ++gi) {
      const int g = bg0 + gi * 2;
#pragma unroll
      for (int j = 0; j < 8; ++j)
        bv[gi][j] = xb[xo + (ci0 + g * 8 + j) * (HW * HW)];
    }

    __syncthreads();

#pragma unroll
    for (int gi = 0; gi < 2; ++gi) {
      const int g = ag0 + gi;
      uint4 pv;
      pv.x = pack2(av[gi][0], av[gi][1]);
      pv.y = pack2(av[gi][2], av[gi][3]);
      pv.z = pack2(av[gi][4], av[gi][5]);
      pv.w = pack2(av[gi][6], av[gi][7]);
      *reinterpret_cast<uint4*>(&As[am * 32 + ((g ^ ((am >> 1) & 3)) << 3)]) = pv;
    }
#pragma unroll
    for (int gi = 0; gi < 2; ++gi) {
      const int g = bg0 + gi * 2;
      uint4 pv;
      pv.x = pack2(bv[gi][0], bv[gi][1]);
      pv.y = pack2(bv[gi][2], bv[gi][3]);
      pv.z = pack2(bv[gi][4], bv[gi][5]);
      pv.w = pack2(bv[gi][6], bv[gi][7]);
      *reinterpret_cast<uint4*>(&Bs[bn * 32 + ((g ^ ((bn >> 1) & 3)) << 3)]) = pv;
    }

    __syncthreads();

    bf16x8 af[4], bfr[4];
    const int g = lane >> 4;
#pragma unroll
    for (int mi = 0; mi < 4; ++mi) {
      const int m = wm * 64 + mi * 16 + (lane & 15);
      af[mi] = *reinterpret_cast<const bf16x8*>(&As[m * 32 + ((g ^ ((m >> 1) & 3)) << 3)]);
    }
#pragma unroll
    for (int ni = 0; ni < 4; ++ni) {
      const int nn = wn * 64 + ni * 16 + (lane & 15);
      bfr[ni] = *reinterpret_cast<const bf16x8*>(&Bs[nn * 32 + ((g ^ ((nn >> 1) & 3)) << 3)]);
    }
#pragma unroll
    for (int mi = 0; mi < 4; ++mi)
#pragma unroll
      for (int ni = 0; ni < 4; ++ni)
        acc[mi][ni] = __builtin_amdgcn_mfma_f32_16x16x32_bf16(af[mi], bfr[ni],
                                                              acc[mi][ni], 0, 0, 0);
  }

#pragma unroll
  for (int ni = 0; ni < 4; ++ni) {
    const unsigned n  = n_base + wn * 64 + ni * 16 + (lane & 15);
    const unsigned b2 = n / NS;
    const unsigned s2 = n - b2 * NS;
    float* op = out + (size_t)b2 * (COUT * NS) + s2
                    + (size_t)(co_base + wm * 64 + (lane >> 4) * 4) * NS;
#pragma unroll
    for (int mi = 0; mi < 4; ++mi)
#pragma unroll
      for (int r = 0; r < 4; ++r)
        op[(mi * 16 + r) * NS] = acc[mi][ni][r];
  }
}

extern "C" void kernel_launch(void* const* d_in, const int* in_sizes, int n_in,
                              void* d_out, int out_size, void* d_ws, size_t ws_size,
                              hipStream_t stream) {
  const float* x = (const float*)d_in[0];   // [32,128,64,64]
  const float* w = (const float*)d_in[1];   // [256,128,3,3]
  float* out = (float*)d_out;               // [32,256,62,62]

  if (ws_size >= WS_NEEDED) {
    unsigned* ap32 = (unsigned*)d_ws;
    unsigned short* Ap = (unsigned short*)d_ws;
    unsigned short* Xp = (unsigned short*)((char*)d_ws + AP_BYTES);
    unsigned* xp32 = (unsigned*)Xp;
    prepack_w<<<576, 256, 0, stream>>>(w, ap32);
    prepack_x<<<32 * HW, 256, 0, stream>>>(x, xp32);
    conv_main<<<dim3(NBLK), 512, 0, stream>>>(Ap, Xp, out);
  } else {
    conv_fallback<<<dim3(2, NTOT / 128), 256, 0, stream>>>(x, w, out);
  }
}

// Round 5
// 117.583 us; speedup vs baseline: 1.0320x; 1.0320x over previous
//
#include <hip/hip_runtime.h>

// Implicit-GEMM conv2d via bf16 MFMA, ws pre-pack + faithful m201-style
// 4-phase/K-tile pipelined schedule with half-tile staging granularity and
// counted vmcnt(4) placed one phase ahead of consumption.
//   A' [256][1152] bf16, k = tap*128+ci   (from w [256][128][3][3] f32)
//   xp [32][64][64][128] bf16 (NHWC)       (from x [32][128][64][64] f32)
// GEMM: M=256, N=123008, K=1152. Tile 256x256xBK64, 512 thr, 8 waves (2Mx4N),
// per-wave 128x64, acc[8][4]. LDS 2 x 64KB.

using bf16x8 = __attribute__((ext_vector_type(8))) __bf16;
using f32x4  = __attribute__((ext_vector_type(4))) float;

constexpr int CIN  = 128;
constexpr int HW   = 64;
constexpr int COUT = 256;
constexpr int OW   = 62;
constexpr int NS   = 62 * 62;          // 3844
constexpr int NTOT = 32 * NS;          // 123008
constexpr int KTOT = 9 * CIN;          // 1152
constexpr int BM = 256, BN = 256, BK = 64;
constexpr int NT = KTOT / BK;          // 18 K-tiles
constexpr int NBLK = (NTOT + BN - 1) / BN;   // 481

constexpr size_t AP_BYTES = (size_t)COUT * KTOT * 2;            // 589824
constexpr size_t XP_BYTES = (size_t)32 * HW * HW * CIN * 2;     // 33554432
constexpr size_t WS_NEEDED = AP_BYTES + XP_BYTES;

constexpr int BUF  = 65536;            // per K-tile buffer: A 32KB + B 32KB
constexpr int BOFF = 32768;            // B offset inside buffer

__device__ __forceinline__ unsigned short f2bf(float f) {
  unsigned u = __float_as_uint(f);
  u += 0x7fffu + ((u >> 16) & 1u);     // RNE
  return (unsigned short)(u >> 16);
}
__device__ __forceinline__ unsigned pack2(float a, float b) {
  return (unsigned)f2bf(a) | ((unsigned)f2bf(b) << 16);
}

__device__ __forceinline__ void gld16(const void* g, void* l) {
  __builtin_amdgcn_global_load_lds(
      (const __attribute__((address_space(1))) unsigned int*)g,
      (__attribute__((address_space(3))) unsigned int*)l, 16, 0, 0);
}

// ---------------- prepack kernels ----------------

__global__ __launch_bounds__(256)
void prepack_w(const float* __restrict__ w, unsigned* __restrict__ ap32) {
  const int idx = blockIdx.x * 256 + threadIdx.x;     // 0..147455
  const int co  = idx / 576;
  const int k2  = idx - co * 576;
  const int k   = k2 * 2;
  const int tap = k >> 7;
  const int ci  = k & 127;
  const float v0 = w[(co * 128 + ci) * 9 + tap];
  const float v1 = w[(co * 128 + ci + 1) * 9 + tap];
  ap32[idx] = pack2(v0, v1);
}

__global__ __launch_bounds__(256)
void prepack_x(const float* __restrict__ x, unsigned* __restrict__ xp32) {
  const int bh = blockIdx.x;           // b*64 + h
  const int b  = bh >> 6, h = bh & 63;
  const int t  = threadIdx.x;
  const int c  = t & 63;               // ci-pair index (ci = 2c, 2c+1)
  const int w0 = (t >> 6) * 16;

  const float* p0 = x + (((size_t)(b * 128 + 2 * c) * HW) + h) * HW + w0;
  const float* p1 = p0 + (size_t)HW * HW;
  float r0[16], r1[16];
#pragma unroll
  for (int j = 0; j < 4; ++j) {
    *reinterpret_cast<float4*>(&r0[j * 4]) = reinterpret_cast<const float4*>(p0)[j];
    *reinterpret_cast<float4*>(&r1[j * 4]) = reinterpret_cast<const float4*>(p1)[j];
  }
  unsigned* o = xp32 + ((size_t)bh * HW + w0) * 64 + c;
#pragma unroll
  for (int j = 0; j < 16; ++j)
    o[j * 64] = pack2(r0[j], r1[j]);
}

// ---------------- main kernel ----------------

__global__ __launch_bounds__(512, 2)
void conv_main(const unsigned short* __restrict__ Ap,
               const unsigned short* __restrict__ Xp,
               float* __restrict__ out) {
  // Buffer layout: rows of 64 bf16 (128B = 8 x 16B slots); LDS slot s of row r
  // holds global k-slot g = s ^ (r&7); staged linearly (source pre-swizzled).
  __shared__ __align__(16) char lds[2 * BUF];   // 128 KiB

  const int tid  = threadIdx.x;
  const int lane = tid & 63;
  const int wid  = tid >> 6;       // 0..7
  const int wm   = wid & 1;        // A half: rows wm*128..+127
  const int wn   = wid >> 1;       // B slice: rows wn*64..+63
  const int n_base = blockIdx.x * BN;

  // ---- staging source offsets (element units); chunk j covers rows j*64..+63
  const int l3  = lane >> 3;
  const int sw8 = ((lane & 7) ^ l3) * 8;     // pre-swizzled slot
  int aoff[4];
  unsigned xoff[4];
#pragma unroll
  for (int j = 0; j < 4; ++j) {
    const int r = j * 64 + wid * 8 + l3;
    aoff[j] = r * KTOT + sw8;
    unsigned n = n_base + r;
    if (n >= NTOT) n = NTOT - 1;             // tail block: clamp (stores guarded)
    const unsigned bi = n / NS;
    const unsigned s0 = n - bi * NS;
    const unsigned oh = s0 / OW;
    const unsigned ww = s0 - oh * OW;
    xoff[j] = ((bi * HW + oh) * HW + ww) * CIN + sw8;
  }

  // ---- fragment read addressing (byte offsets within buffer) ----
  const int fr = lane & 15;
  const int gl = lane >> 4;
  const int s0b = ((gl)     ^ (fr & 7)) * 16;   // kk=0 slot
  const int s1b = ((4 + gl) ^ (fr & 7)) * 16;   // kk=1 slot
  const int abase = (wm * 128 + fr) * 128;
  const int bbase = BOFF + (wn * 64 + fr) * 128;

  f32x4 acc[8][4] = {};
  bf16x8 aq[8];          // [mi * 2 + kk], current m-quadrant
  bf16x8 b0q[4], b1q[4]; // [ni * 2 + kk], n-quadrant 0 / 1

  // half-tile stagers: 2 x gld16 per thread per call
  auto STAGE_A_HALF = [&](int tt, int h, char* dst) {
#pragma unroll
    for (int jj = 0; jj < 2; ++jj) {
      const int j = h * 2 + jj;
      gld16(Ap + aoff[j] + tt * 64, dst + (j * 64 + wid * 8) * 128);
    }
  };
  auto STAGE_B_HALF = [&](int tt, int h, char* dst) {
    const int tap = tt >> 1;
    const int kh  = tap / 3;
    const int kw  = tap - kh * 3;
    const int xk  = (kh * HW + kw) * CIN + (tt & 1) * 64;
#pragma unroll
    for (int jj = 0; jj < 2; ++jj) {
      const int j = h * 2 + jj;
      gld16(Xp + xoff[j] + xk, dst + BOFF + (j * 64 + wid * 8) * 128);
    }
  };

  auto LOAD_A = [&](const char* cur, int mq) {
#pragma unroll
    for (int mi = 0; mi < 4; ++mi) {
      aq[mi * 2 + 0] = *reinterpret_cast<const bf16x8*>(cur + abase + mq * 8192 + mi * 2048 + s0b);
      aq[mi * 2 + 1] = *reinterpret_cast<const bf16x8*>(cur + abase + mq * 8192 + mi * 2048 + s1b);
    }
  };
  auto LOAD_B = [&](const char* cur, int nq, bf16x8* bq) {
#pragma unroll
    for (int ni = 0; ni < 2; ++ni) {
      bq[ni * 2 + 0] = *reinterpret_cast<const bf16x8*>(cur + bbase + nq * 4096 + ni * 2048 + s0b);
      bq[ni * 2 + 1] = *reinterpret_cast<const bf16x8*>(cur + bbase + nq * 4096 + ni * 2048 + s1b);
    }
  };
  auto MFMA16 = [&](int mq, int nq, const bf16x8* bq) {
    __builtin_amdgcn_s_setprio(1);
#pragma unroll
    for (int mi = 0; mi < 4; ++mi)
#pragma unroll
      for (int ni = 0; ni < 2; ++ni)
#pragma unroll
        for (int kk = 0; kk < 2; ++kk)
          acc[mq * 4 + mi][nq * 2 + ni] = __builtin_amdgcn_mfma_f32_16x16x32_bf16(
              aq[mi * 2 + kk], bq[ni * 2 + kk], acc[mq * 4 + mi][nq * 2 + ni], 0, 0, 0);
    __builtin_amdgcn_s_setprio(0);
  };

  // ---- prologue: A(0)+B(0) -> buf0, B(1) -> buf1; wait A0/B0 (B1 in flight)
  {
    char* b0 = lds;
    char* b1 = lds + BUF;
    STAGE_A_HALF(0, 0, b0); STAGE_A_HALF(0, 1, b0);
    STAGE_B_HALF(0, 0, b0); STAGE_B_HALF(0, 1, b0);
    STAGE_B_HALF(1, 0, b1); STAGE_B_HALF(1, 1, b1);
    asm volatile("s_waitcnt vmcnt(4)" ::: "memory");
    __builtin_amdgcn_s_barrier();
  }

#pragma unroll
  for (int t = 0; t < NT; ++t) {
    const char* cur = lds + (t & 1) * BUF;
    char* curw = lds + (t & 1) * BUF;
    char* nxt  = lds + ((t + 1) & 1) * BUF;

    // ---- Phase 1: reads A(m0)+B(n0); stage A(t+1).h0; MFMA (m0,n0) ----
    LOAD_A(cur, 0);
    LOAD_B(cur, 0, b0q);
    if (t + 1 < NT) STAGE_A_HALF(t + 1, 0, nxt);
    asm volatile("s_waitcnt lgkmcnt(8)" ::: "memory");
    __builtin_amdgcn_s_barrier();
    asm volatile("s_waitcnt lgkmcnt(0)" ::: "memory");
    __builtin_amdgcn_sched_barrier(0);
    MFMA16(0, 0, b0q);
    __builtin_amdgcn_s_barrier();

    // ---- Phase 2: reads B(n1); stage A(t+1).h1; MFMA (m0,n1) ----
    LOAD_B(cur, 1, b1q);
    if (t + 1 < NT) STAGE_A_HALF(t + 1, 1, nxt);
    __builtin_amdgcn_s_barrier();
    asm volatile("s_waitcnt lgkmcnt(0)" ::: "memory");
    __builtin_amdgcn_sched_barrier(0);
    MFMA16(0, 1, b1q);
    __builtin_amdgcn_s_barrier();

    // ---- Phase 3: reads A(m1); stage B(t+2).h0 into cur.B; MFMA (m1,n1) ----
    LOAD_A(cur, 1);
    if (t + 2 < NT) STAGE_B_HALF(t + 2, 0, curw);
    __builtin_amdgcn_s_barrier();
    asm volatile("s_waitcnt lgkmcnt(0)" ::: "memory");
    __builtin_amdgcn_sched_barrier(0);
    MFMA16(1, 1, b1q);
    __builtin_amdgcn_s_barrier();

    // ---- Phase 4: stage B(t+2).h1; counted wait for tile t+1; MFMA (m1,n0) ----
    if (t + 2 < NT) STAGE_B_HALF(t + 2, 1, curw);
    if (t + 1 < NT) {
      if (t + 2 < NT) asm volatile("s_waitcnt vmcnt(4)" ::: "memory");
      else            asm volatile("s_waitcnt vmcnt(0)" ::: "memory");
    }
    __builtin_amdgcn_s_barrier();
    MFMA16(1, 0, b0q);
    __builtin_amdgcn_s_barrier();
  }

  // ---- epilogue: D col = lane&15 (n), row = (lane>>4)*4 + r (co) ----
#pragma unroll
  for (int ni = 0; ni < 4; ++ni) {
    const unsigned n = n_base + wn * 64 + ni * 16 + fr;
    if (n >= NTOT) continue;
    const unsigned b2 = n / NS;
    const unsigned s2 = n - b2 * NS;
    float* op = out + (size_t)b2 * (COUT * NS) + s2
                    + (size_t)(wm * 128 + gl * 4) * NS;
#pragma unroll
    for (int mi = 0; mi < 8; ++mi)
#pragma unroll
      for (int r = 0; r < 4; ++r)
        op[(mi * 16 + r) * NS] = acc[mi][ni][r];
  }
}

// ---------------- fallback (no-ws path, round-1 proven) ----------------

__global__ __launch_bounds__(256)
void conv_fallback(const float* __restrict__ x, const float* __restrict__ w,
                   float* __restrict__ out) {
  __shared__ __align__(16) unsigned short As[128 * 32];
  __shared__ __align__(16) unsigned short Bs[128 * 32];

  const int t    = threadIdx.x;
  const int lane = t & 63;
  const int wid  = t >> 6;
  const int wm   = wid >> 1;
  const int wn   = wid & 1;
  const int co_base = blockIdx.x * 128;
  const int n_base  = blockIdx.y * 128;

  const int bn  = t & 127;
  const int bg0 = t >> 7;
  const unsigned n0   = n_base + bn;
  const unsigned bidx = n0 / NS;
  const unsigned s0   = n0 - bidx * NS;
  const unsigned oh   = s0 / OW;
  const unsigned ow   = s0 - oh * OW;
  const float* xb = x + (bidx * (CIN * HW * HW) + oh * HW + ow);

  const int am  = t & 127;
  const int ag0 = (t >> 7) * 2;
  const float* wb = w + (co_base + am) * KTOT;

  f32x4 acc[4][4] = {};

  for (int ks = 0; ks < 36; ++ks) {
    const int tap = ks >> 2;
    const int ci0 = (ks & 3) * 32;
    const int kh  = tap / 3;
    const int kw  = tap - kh * 3;
    const int xo  = kh * HW + kw;

    float av[2][8], bv[2][8];
#pragma unroll
    for (int gi = 0; gi < 2; ++gi) {
      const int g = ag0 + gi;
#pragma unroll
      for (int j = 0; j < 8; ++j)
        av[gi][j] = wb[(ci0 + g * 8 + j) * 9 + tap];
    }
#pragma unroll
    for (int gi = 0; gi < 2; ++gi) {
      const int g = bg0 + gi * 2;
#pragma unroll
      for (int j = 0; j < 8; ++j)
        bv[gi][j] = xb[xo + (ci0 + g * 8 + j) * (HW * HW)];
    }

    __syncthreads();

#pragma unroll
    for (int gi = 0; gi < 2; ++gi) {
      const int g = ag0 + gi;
      uint4 pv;
      pv.x = pack2(av[gi][0], av[gi][1]);
      pv.y = pack2(av[gi][2], av[gi][3]);
      pv.z = pack2(av[gi][4], av[gi][5]);
      pv.w = pack2(av[gi][6], av[gi][7]);
      *reinterpret_cast<uint4*>(&As[am * 32 + ((g ^ ((am >> 1) & 3)) << 3)]) = pv;
    }
#pragma unroll
    for (int gi = 0; gi < 2; ++gi) {
      const int g = bg0 + gi * 2;
      uint4 pv;
      pv.x = pack2(bv[gi][0], bv[gi][1]);
      pv.y = pack2(bv[gi][2], bv[gi][3]);
      pv.z = pack2(bv[gi][4], bv[gi][5]);
      pv.w = pack2(bv[gi][6], bv[gi][7]);
      *reinterpret_cast<uint4*>(&Bs[bn * 32 + ((g ^ ((bn >> 1) & 3)) << 3)]) = pv;
    }

    __syncthreads();

    bf16x8 af[4], bfr[4];
    const int g = lane >> 4;
#pragma unroll
    for (int mi = 0; mi < 4; ++mi) {
      const int m = wm * 64 + mi * 16 + (lane & 15);
      af[mi] = *reinterpret_cast<const bf16x8*>(&As[m * 32 + ((g ^ ((m >> 1) & 3)) << 3)]);
    }
#pragma unroll
    for (int ni = 0; ni < 4; ++ni) {
      const int nn = wn * 64 + ni * 16 + (lane & 15);
      bfr[ni] = *reinterpret_cast<const bf16x8*>(&Bs[nn * 32 + ((g ^ ((nn >> 1) & 3)) << 3)]);
    }
#pragma unroll
    for (int mi = 0; mi < 4; ++mi)
#pragma unroll
      for (int ni = 0; ni < 4; ++ni)
        acc[mi][ni] = __builtin_amdgcn_mfma_f32_16x16x32_bf16(af[mi], bfr[ni],
                                                              acc[mi][ni], 0, 0, 0);
  }

#pragma unroll
  for (int ni = 0; ni < 4; ++ni) {
    const unsigned n  = n_base + wn * 64 + ni * 16 + (lane & 15);
    const unsigned b2 = n / NS;
    const unsigned s2 = n - b2 * NS;
    float* op = out + (size_t)b2 * (COUT * NS) + s2
                    + (size_t)(co_base + wm * 64 + (lane >> 4) * 4) * NS;
#pragma unroll
    for (int mi = 0; mi < 4; ++mi)
#pragma unroll
      for (int r = 0; r < 4; ++r)
        op[(mi * 16 + r) * NS] = acc[mi][ni][r];
  }
}

extern "C" void kernel_launch(void* const* d_in, const int* in_sizes, int n_in,
                              void* d_out, int out_size, void* d_ws, size_t ws_size,
                              hipStream_t stream) {
  const float* x = (const float*)d_in[0];   // [32,128,64,64]
  const float* w = (const float*)d_in[1];   // [256,128,3,3]
  float* out = (float*)d_out;               // [32,256,62,62]

  if (ws_size >= WS_NEEDED) {
    unsigned* ap32 = (unsigned*)d_ws;
    unsigned short* Ap = (unsigned short*)d_ws;
    unsigned short* Xp = (unsigned short*)((char*)d_ws + AP_BYTES);
    unsigned* xp32 = (unsigned*)Xp;
    prepack_w<<<576, 256, 0, stream>>>(w, ap32);
    prepack_x<<<32 * HW, 256, 0, stream>>>(x, xp32);
    conv_main<<<dim3(NBLK), 512, 0, stream>>>(Ap, Xp, out);
  } else {
    conv_fallback<<<dim3(2, NTOT / 128), 256, 0, stream>>>(x, w, out);
  }
}

// Round 6
// 110.215 us; speedup vs baseline: 1.1010x; 1.0669x over previous
//
#include <hip/hip_runtime.h>

// Implicit-GEMM conv2d via bf16 MFMA (32x32x16), ws pre-pack.
// GEMM: M=256=Cout, N=123008, K=1152 (k = tap*128+ci).
// Tile 128x128xBK64, 256 thr / 4 waves (2Mx2N), wave tile 64x64 = 2x2 of
// 32x32x16. LDS 2 x 32KB double-buffer -> 2 blocks/CU (cross-block overlap).
// One raw s_barrier per K-tile; stage(t+1) issued right after it.
//   A' [256][1152] bf16   (from w [256][128][3][3] f32)
//   xp [32][64][64][128] bf16 (NHWC, from x [32][128][64][64] f32)

using bf16x8 = __attribute__((ext_vector_type(8))) __bf16;
using f32x4  = __attribute__((ext_vector_type(4))) float;
using f32x16 = __attribute__((ext_vector_type(16))) float;

constexpr int CIN  = 128;
constexpr int HW   = 64;
constexpr int COUT = 256;
constexpr int OW   = 62;
constexpr int NS   = 62 * 62;          // 3844
constexpr int NTOT = 32 * NS;          // 123008
constexpr int KTOT = 9 * CIN;          // 1152
constexpr int BM = 128, BN = 128, BK = 64;
constexpr int NT = KTOT / BK;          // 18 K-tiles
constexpr int NWG = 2 * (NTOT / BN);   // 1922

constexpr size_t AP_BYTES = (size_t)COUT * KTOT * 2;            // 589824
constexpr size_t XP_BYTES = (size_t)32 * HW * HW * CIN * 2;     // 33554432
constexpr size_t WS_NEEDED = AP_BYTES + XP_BYTES;

constexpr int BUF  = 32768;            // per K-tile buffer: A 16KB + B 16KB
constexpr int BOFF = 16384;            // B offset inside buffer

__device__ __forceinline__ unsigned short f2bf(float f) {
  unsigned u = __float_as_uint(f);
  u += 0x7fffu + ((u >> 16) & 1u);     // RNE
  return (unsigned short)(u >> 16);
}
__device__ __forceinline__ unsigned pack2(float a, float b) {
  return (unsigned)f2bf(a) | ((unsigned)f2bf(b) << 16);
}

__device__ __forceinline__ void gld16(const void* g, void* l) {
  __builtin_amdgcn_global_load_lds(
      (const __attribute__((address_space(1))) unsigned int*)g,
      (__attribute__((address_space(3))) unsigned int*)l, 16, 0, 0);
}

// ---------------- prepack kernels ----------------

__global__ __launch_bounds__(256)
void prepack_w(const float* __restrict__ w, unsigned* __restrict__ ap32) {
  const int idx = blockIdx.x * 256 + threadIdx.x;     // 0..147455
  const int co  = idx / 576;
  const int k2  = idx - co * 576;
  const int k   = k2 * 2;
  const int tap = k >> 7;
  const int ci  = k & 127;
  const float v0 = w[(co * 128 + ci) * 9 + tap];
  const float v1 = w[(co * 128 + ci + 1) * 9 + tap];
  ap32[idx] = pack2(v0, v1);
}

__global__ __launch_bounds__(256)
void prepack_x(const float* __restrict__ x, unsigned* __restrict__ xp32) {
  const int bh = blockIdx.x;           // b*64 + h
  const int b  = bh >> 6, h = bh & 63;
  const int t  = threadIdx.x;
  const int c  = t & 63;               // ci-pair index (ci = 2c, 2c+1)
  const int w0 = (t >> 6) * 16;

  const float* p0 = x + (((size_t)(b * 128 + 2 * c) * HW) + h) * HW + w0;
  const float* p1 = p0 + (size_t)HW * HW;
  float r0[16], r1[16];
#pragma unroll
  for (int j = 0; j < 4; ++j) {
    *reinterpret_cast<float4*>(&r0[j * 4]) = reinterpret_cast<const float4*>(p0)[j];
    *reinterpret_cast<float4*>(&r1[j * 4]) = reinterpret_cast<const float4*>(p1)[j];
  }
  unsigned* o = xp32 + ((size_t)bh * HW + w0) * 64 + c;
#pragma unroll
  for (int j = 0; j < 16; ++j)
    o[j * 64] = pack2(r0[j], r1[j]);
}

// ---------------- main kernel ----------------

__global__ __launch_bounds__(256, 2)
void conv_main(const unsigned short* __restrict__ Ap,
               const unsigned short* __restrict__ Xp,
               float* __restrict__ out) {
  // Buffer: rows of 64 bf16 (128B = 8 x 16B slots); LDS slot s of row r holds
  // global k-slot s ^ (r&7); staged linearly (source pre-swizzled).
  __shared__ __align__(16) char lds[2 * BUF];   // 64 KiB -> 2 blocks/CU

  const int tid  = threadIdx.x;
  const int lane = tid & 63;
  const int wid  = tid >> 6;       // 0..3
  const int wm   = wid >> 1;       // M half (64 rows)
  const int wn   = wid & 1;        // N half (64 cols)

  // ---- bijective XCD swizzle over flattened grid (pair co-halves) ----
  int wg;
  {
    const int f = blockIdx.x;                  // 0..NWG-1
    constexpr int q = NWG / 8, r = NWG % 8;    // 240, 2
    const int xc = f % 8, p = f / 8;
    wg = (xc < r ? xc * (q + 1) : r * (q + 1) + (xc - r) * q) + p;
  }
  const int co_base = (wg & 1) * BM;
  const int n_base  = (wg >> 1) * BN;

  // ---- staging source offsets; chunk = wid*4+q covers rows (wid*32+q*8)+l3
  const int l3  = lane >> 3;                 // 0..7
  const int sw8 = ((lane & 7) ^ l3) * 8;     // pre-swizzled slot (elements)
  int aoff[4];
  unsigned xoff[4];
#pragma unroll
  for (int q = 0; q < 4; ++q) {
    const int rr = wid * 32 + q * 8 + l3;    // 0..127
    aoff[q] = (co_base + rr) * KTOT + sw8;
    const unsigned n  = n_base + rr;         // < NTOT always (no tail)
    const unsigned bi = n / NS;
    const unsigned s0 = n - bi * NS;
    const unsigned oh = s0 / OW;
    const unsigned ww = s0 - oh * OW;
    xoff[q] = ((bi * HW + oh) * HW + ww) * CIN + sw8;
  }

  // ---- fragment read addressing ----
  const int cl = lane & 31;        // MFMA row/col within 32-tile
  const int gl = lane >> 5;        // k-group
  int sA[4];
#pragma unroll
  for (int kf = 0; kf < 4; ++kf)
    sA[kf] = ((kf * 2 + gl) ^ (lane & 7)) * 16;   // swizzled slot byte offset
  const int abase = (wm * 64 + cl) * 128;
  const int bbase = BOFF + (wn * 64 + cl) * 128;

  f32x16 acc[2][2] = {};

  auto STAGE = [&](int t, char* dst) {
    const int tap = t >> 1;
    const int kh  = tap / 3;
    const int kw  = tap - kh * 3;
    const int ak  = tap * CIN + (t & 1) * 64;
    const int xk  = (kh * HW + kw) * CIN + (t & 1) * 64;
#pragma unroll
    for (int q = 0; q < 4; ++q)
      gld16(Ap + aoff[q] + ak, dst + (wid * 32 + q * 8) * 128);
#pragma unroll
    for (int q = 0; q < 4; ++q)
      gld16(Xp + xoff[q] + xk, dst + BOFF + (wid * 32 + q * 8) * 128);
  };

  STAGE(0, lds);

#pragma unroll
  for (int t = 0; t < NT; ++t) {
    const char* cur = lds + (t & 1) * BUF;
    asm volatile("s_waitcnt vmcnt(0)" ::: "memory");   // stage(t) landed
    __builtin_amdgcn_s_barrier();                      // readers of buf(t-1) done
    if (t + 1 < NT) STAGE(t + 1, lds + ((t + 1) & 1) * BUF);

    bf16x8 a[2][4], b[2][4];
#pragma unroll
    for (int mt = 0; mt < 2; ++mt)
#pragma unroll
      for (int kf = 0; kf < 4; ++kf)
        a[mt][kf] = *reinterpret_cast<const bf16x8*>(cur + abase + mt * 4096 + sA[kf]);
#pragma unroll
    for (int nt = 0; nt < 2; ++nt)
#pragma unroll
      for (int kf = 0; kf < 4; ++kf)
        b[nt][kf] = *reinterpret_cast<const bf16x8*>(cur + bbase + nt * 4096 + sA[kf]);

#pragma unroll
    for (int kf = 0; kf < 4; ++kf)
#pragma unroll
      for (int mt = 0; mt < 2; ++mt)
#pragma unroll
        for (int nt = 0; nt < 2; ++nt)
          acc[mt][nt] = __builtin_amdgcn_mfma_f32_32x32x16_bf16(
              a[mt][kf], b[nt][kf], acc[mt][nt], 0, 0, 0);
  }

  // ---- epilogue: 32x32 C/D layout col=lane&31, row=(r&3)+8*(r>>2)+4*gl ----
#pragma unroll
  for (int mt = 0; mt < 2; ++mt)
#pragma unroll
    for (int nt = 0; nt < 2; ++nt) {
      const unsigned n  = n_base + wn * 64 + nt * 32 + cl;
      const unsigned b2 = n / NS;
      const unsigned s2 = n - b2 * NS;
      float* op = out + (size_t)b2 * (COUT * NS) + s2
                      + (size_t)(co_base + wm * 64 + mt * 32 + gl * 4) * NS;
#pragma unroll
      for (int r = 0; r < 16; ++r)
        op[((r & 3) + 8 * (r >> 2)) * NS] = acc[mt][nt][r];
    }
}

// ---------------- fallback (no-ws path, round-1 proven) ----------------

__global__ __launch_bounds__(256)
void conv_fallback(const float* __restrict__ x, const float* __restrict__ w,
                   float* __restrict__ out) {
  __shared__ __align__(16) unsigned short As[128 * 32];
  __shared__ __align__(16) unsigned short Bs[128 * 32];

  const int t    = threadIdx.x;
  const int lane = t & 63;
  const int wid  = t >> 6;
  const int wm   = wid >> 1;
  const int wn   = wid & 1;
  const int co_base = blockIdx.x * 128;
  const int n_base  = blockIdx.y * 128;

  const int bn  = t & 127;
  const int bg0 = t >> 7;
  const unsigned n0   = n_base + bn;
  const unsigned bidx = n0 / NS;
  const unsigned s0   = n0 - bidx * NS;
  const unsigned oh   = s0 / OW;
  const unsigned ow   = s0 - oh * OW;
  const float* xb = x + (bidx * (CIN * HW * HW) + oh * HW + ow);

  const int am  = t & 127;
  const int ag0 = (t >> 7) * 2;
  const float* wb = w + (co_base + am) * KTOT;

  f32x4 acc[4][4] = {};

  for (int ks = 0; ks < 36; ++ks) {
    const int tap = ks >> 2;
    const int ci0 = (ks & 3) * 32;
    const int kh  = tap / 3;
    const int kw  = tap - kh * 3;
    const int xo  = kh * HW + kw;

    float av[2][8], bv[2][8];
#pragma unroll
    for (int gi = 0; gi < 2; ++gi) {
      const int g = ag0 + gi;
#pragma unroll
      for (int j = 0; j < 8; ++j)
        av[gi][j] = wb[(ci0 + g * 8 + j) * 9 + tap];
    }
#pragma unroll
    for (int gi = 0; gi < 2; ++gi) {
      const int g = bg0 + gi * 2;
#pragma unroll
      for (int j = 0; j < 8; ++j)
        bv[gi][j] = xb[xo + (ci0 + g * 8 + j) * (HW * HW)];
    }

    __syncthreads();

#pragma unroll
    for (int gi = 0; gi < 2; ++gi) {
      const int g = ag0 + gi;
      uint4 pv;
      pv.x = pack2(av[gi][0], av[gi][1]);
      pv.y = pack2(av[gi][2], av[gi][3]);
      pv.z = pack2(av[gi][4], av[gi][5]);
      pv.w = pack2(av[gi][6], av[gi][7]);
      *reinterpret_cast<uint4*>(&As[am * 32 + ((g ^ ((am >> 1) & 3)) << 3)]) = pv;
    }
#pragma unroll
    for (int gi = 0; gi < 2; ++gi) {
      const int g = bg0 + gi * 2;
      uint4 pv;
      pv.x = pack2(bv[gi][0], bv[gi][1]);
      pv.y = pack2(bv[gi][2], bv[gi][3]);
      pv.z = pack2(bv[gi][4], bv[gi][5]);
      pv.w = pack2(bv[gi][6], bv[gi][7]);
      *reinterpret_cast<uint4*>(&Bs[bn * 32 + ((g ^ ((bn >> 1) & 3)) << 3)]) = pv;
    }

    __syncthreads();

    bf16x8 af[4], bfr[4];
    const int g = lane >> 4;
#pragma unroll
    for (int mi = 0; mi < 4; ++mi) {
      const int m = wm * 64 + mi * 16 + (lane & 15);
      af[mi] = *reinterpret_cast<const bf16x8*>(&As[m * 32 + ((g ^ ((m >> 1) & 3)) << 3)]);
    }
#pragma unroll
    for (int ni = 0; ni < 4; ++ni) {
      const int nn = wn * 64 + ni * 16 + (lane & 15);
      bfr[ni] = *reinterpret_cast<const bf16x8*>(&Bs[nn * 32 + ((g ^ ((nn >> 1) & 3)) << 3)]);
    }
#pragma unroll
    for (int mi = 0; mi < 4; ++mi)
#pragma unroll
      for (int ni = 0; ni < 4; ++ni)
        acc[mi][ni] = __builtin_amdgcn_mfma_f32_16x16x32_bf16(af[mi], bfr[ni],
                                                              acc[mi][ni], 0, 0, 0);
  }

#pragma unroll
  for (int ni = 0; ni < 4; ++ni) {
    const unsigned n  = n_base + wn * 64 + ni * 16 + (lane & 15);
    const unsigned b2 = n / NS;
    const unsigned s2 = n - b2 * NS;
    float* op = out + (size_t)b2 * (COUT * NS) + s2
                    + (size_t)(co_base + wm * 64 + (lane >> 4) * 4) * NS;
#pragma unroll
    for (int mi = 0; mi < 4; ++mi)
#pragma unroll
      for (int r = 0; r < 4; ++r)
        op[(mi * 16 + r) * NS] = acc[mi][ni][r];
  }
}

extern "C" void kernel_launch(void* const* d_in, const int* in_sizes, int n_in,
                              void* d_out, int out_size, void* d_ws, size_t ws_size,
                              hipStream_t stream) {
  const float* x = (const float*)d_in[0];   // [32,128,64,64]
  const float* w = (const float*)d_in[1];   // [256,128,3,3]
  float* out = (float*)d_out;               // [32,256,62,62]

  if (ws_size >= WS_NEEDED) {
    unsigned* ap32 = (unsigned*)d_ws;
    unsigned short* Ap = (unsigned short*)d_ws;
    unsigned short* Xp = (unsigned short*)((char*)d_ws + AP_BYTES);
    unsigned* xp32 = (unsigned*)Xp;
    prepack_w<<<576, 256, 0, stream>>>(w, ap32);
    prepack_x<<<32 * HW, 256, 0, stream>>>(x, xp32);
    conv_main<<<dim3(NWG), 256, 0, stream>>>(Ap, Xp, out);
  } else {
    conv_fallback<<<dim3(2, NTOT / 128), 256, 0, stream>>>(x, w, out);
  }
}